// Round 6
// baseline (693.540 us; speedup 1.0000x reference)
//
#include <hip/hip_runtime.h>
#include <hip/hip_bf16.h>
#include <stdint.h>

// SelfAttention: B=4, N=4096, D=1024, causal, fp32 in/out.
// R6: one-window read-ahead in gemm8p + pv8p (ds_reads for subtile s+1 issued
// before MFMA of subtile s -> counted lgkmcnt, LDS reads hide under MFMA).
// Barriers: gemm8p 8->4 per K-tile, pv8p 4->2. vmcnt(4) at w4 (gemm8p),
// vmcnt(2) per tile (pv8p); never 0 mid-stream.

typedef __attribute__((ext_vector_type(8))) short short8;
typedef __attribute__((ext_vector_type(4))) float float4v;

__device__ inline unsigned short f2b(float f) {
  union { float f; unsigned u; } v; v.f = f;
  unsigned r = (v.u + 0x7fffu + ((v.u >> 16) & 1u)) >> 16;
  return (unsigned short)r;
}
__device__ inline float b2f(unsigned short b) {
  union { unsigned u; float f; } v; v.u = ((unsigned)b) << 16;
  return v.f;
}

typedef const __attribute__((address_space(1))) unsigned int* gptr_t;
typedef __attribute__((address_space(3))) unsigned int* lptr_t;

__device__ inline void gload_lds16(const unsigned short* g, unsigned short* l) {
  __builtin_amdgcn_global_load_lds((gptr_t)(const void*)g, (lptr_t)(void*)l, 16, 0, 0);
}

// ---------------- f32 -> bf16 conversion, all 4 tensors in one launch --------
__global__ __launch_bounds__(256) void cvt_all(const float* __restrict__ x,
                                               const float* __restrict__ wq,
                                               const float* __restrict__ wk,
                                               const float* __restrict__ wv,
                                               unsigned short* __restrict__ xb,
                                               unsigned short* __restrict__ wb) {
  const float* src;
  unsigned short* dst;
  long n, i0, stride;
  if (blockIdx.x < 2048) {
    src = x; dst = xb; n = 16384L * 1024;
    i0 = ((long)blockIdx.x * 256 + threadIdx.x) * 4;
    stride = 2048L * 256 * 4;
  } else {
    int wsec = (blockIdx.x - 2048) >> 8;
    int blk = (blockIdx.x - 2048) & 255;
    src = wsec == 0 ? wq : (wsec == 1 ? wk : wv);
    dst = wb + (long)wsec * 1024 * 1024;
    n = 1024L * 1024;
    i0 = ((long)blk * 256 + threadIdx.x) * 4;
    stride = 256L * 256 * 4;
  }
  for (long i = i0; i < n; i += stride) {
    float4 f = *(const float4*)&src[i];
    union { unsigned short u[4]; uint2 v; } o;
    o.u[0] = f2b(f.x); o.u[1] = f2b(f.y); o.u[2] = f2b(f.z); o.u[3] = f2b(f.w);
    *(uint2*)&dst[i] = o.v;
  }
}

// ================= 256x256 / BK=64 / 8-wave read-ahead GEMM (QKV + S) =========
__device__ __forceinline__ void stage_half(const unsigned short* __restrict__ g,
                                           int grow0, int tile, int kk,
                                           char* tb, int tid) {
  const int kc = tile * 64 + kk * 32;
#pragma unroll
  for (int j = 0; j < 2; j++) {
    int c = j * 512 + tid;
    int lc = c ^ ((c >> 3) & 3);  // inverse of read-side swizzle, chunk-granular
    gload_lds16(g + (long)(grow0 + (lc >> 2)) * 1024 + kc + (lc & 3) * 8,
                (unsigned short*)(tb + kk * 16384 + (j * 512 + (tid & 448)) * 16));
  }
}

// LDS read offsets: o = base + kk*16384 + frag*1024; XOR swizzle mask is
// lane-only (bits 7-8 of o come solely from lr) -> folded into base.
#define LDA(dst, TB, kk, mi) dst = *(const short8*)((TB) + baseA + (kk) * 16384 + (mi) * 1024)
#define LDB(dst, TB, kk, ni) dst = *(const short8*)((TB) + baseB + (kk) * 16384 + (ni) * 1024)

#define MF(x, y, z) __builtin_amdgcn_mfma_f32_16x16x32_bf16(x, y, z, 0, 0, 0)
#define MM4x4(x0, x1, x2, x3, y0, y1, y2, y3, M0) \
  acc[M0 + 0][0] = MF(x0, y0, acc[M0 + 0][0]); \
  acc[M0 + 0][1] = MF(x0, y1, acc[M0 + 0][1]); \
  acc[M0 + 0][2] = MF(x0, y2, acc[M0 + 0][2]); \
  acc[M0 + 0][3] = MF(x0, y3, acc[M0 + 0][3]); \
  acc[M0 + 1][0] = MF(x1, y0, acc[M0 + 1][0]); \
  acc[M0 + 1][1] = MF(x1, y1, acc[M0 + 1][1]); \
  acc[M0 + 1][2] = MF(x1, y2, acc[M0 + 1][2]); \
  acc[M0 + 1][3] = MF(x1, y3, acc[M0 + 1][3]); \
  acc[M0 + 2][0] = MF(x2, y0, acc[M0 + 2][0]); \
  acc[M0 + 2][1] = MF(x2, y1, acc[M0 + 2][1]); \
  acc[M0 + 2][2] = MF(x2, y2, acc[M0 + 2][2]); \
  acc[M0 + 2][3] = MF(x2, y3, acc[M0 + 2][3]); \
  acc[M0 + 3][0] = MF(x3, y0, acc[M0 + 3][0]); \
  acc[M0 + 3][1] = MF(x3, y1, acc[M0 + 3][1]); \
  acc[M0 + 3][2] = MF(x3, y2, acc[M0 + 3][2]); \
  acc[M0 + 3][3] = MF(x3, y3, acc[M0 + 3][3]);

// Read-ahead K-tile: window w executes MFMA on regs loaded in window w-1 while
// issuing window w+1's ds_reads. w4 certifies tile t+1 (vmcnt(4)) then issues
// its s1 reads. Stage plan: w1 A(t+1)k1->OA, w2 B(t+2)k0->CB, w3 A(t+2)k0->CA,
// w4 B(t+2)k1->CB. Each stage lands >=1 barrier after target region's reads
// are lgkmcnt-certified (certification = pre-MFMA wait, before that window's
// barrier).
#define KTILE_RA(CA, CB, OA, OB, t) do { \
  /* w1: MFMA kk0 m0-3; read kk0 m4-7 */ \
  LDA(A4r, CA, 0, 4); LDA(A5r, CA, 0, 5); LDA(A6r, CA, 0, 6); LDA(A7r, CA, 0, 7); \
  if ((t) + 1 < NT) stage_half(A, rowA0, (t) + 1, 1, OA, tid); \
  __builtin_amdgcn_s_setprio(1); MM4x4(A0r, A1r, A2r, A3r, B00, B01, B02, B03, 0); __builtin_amdgcn_s_setprio(0); \
  __builtin_amdgcn_s_barrier(); \
  /* w2: MFMA kk0 m4-7; read kk1 B + kk1 m0-3 */ \
  LDB(B10, CB, 1, 0); LDB(B11, CB, 1, 1); LDB(B12, CB, 1, 2); LDB(B13, CB, 1, 3); \
  LDA(A0r, CA, 1, 0); LDA(A1r, CA, 1, 1); LDA(A2r, CA, 1, 2); LDA(A3r, CA, 1, 3); \
  if ((t) + 2 < NT) stage_half(Bm, rowB0, (t) + 2, 0, CB, tid); \
  __builtin_amdgcn_s_setprio(1); MM4x4(A4r, A5r, A6r, A7r, B00, B01, B02, B03, 4); __builtin_amdgcn_s_setprio(0); \
  __builtin_amdgcn_s_barrier(); \
  /* w3: MFMA kk1 m0-3; read kk1 m4-7 */ \
  LDA(A4r, CA, 1, 4); LDA(A5r, CA, 1, 5); LDA(A6r, CA, 1, 6); LDA(A7r, CA, 1, 7); \
  if ((t) + 2 < NT) stage_half(A, rowA0, (t) + 2, 0, CA, tid); \
  __builtin_amdgcn_s_setprio(1); MM4x4(A0r, A1r, A2r, A3r, B10, B11, B12, B13, 0); __builtin_amdgcn_s_setprio(0); \
  __builtin_amdgcn_s_barrier(); \
  /* w4: certify tile t+1, read its s1; MFMA kk1 m4-7 */ \
  if ((t) + 1 < NT) { \
    if ((t) + 2 < NT) { asm volatile("s_waitcnt vmcnt(4)" ::: "memory"); } \
    else              { asm volatile("s_waitcnt vmcnt(0)" ::: "memory"); } \
    LDB(B00, OB, 0, 0); LDB(B01, OB, 0, 1); LDB(B02, OB, 0, 2); LDB(B03, OB, 0, 3); \
    LDA(A0r, OA, 0, 0); LDA(A1r, OA, 0, 1); LDA(A2r, OA, 0, 2); LDA(A3r, OA, 0, 3); \
  } \
  if ((t) + 2 < NT) stage_half(Bm, rowB0, (t) + 2, 1, CB, tid); \
  __builtin_amdgcn_s_setprio(1); MM4x4(A4r, A5r, A6r, A7r, B10, B11, B12, B13, 4); __builtin_amdgcn_s_setprio(0); \
  __builtin_amdgcn_s_barrier(); \
} while (0)

template <int MODE>
__global__ __launch_bounds__(512, 2) void gemm8p(
    const unsigned short* __restrict__ Ag, const unsigned short* __restrict__ Bg,
    const float* __restrict__ b0v, const float* __restrict__ b1v,
    const float* __restrict__ b2v, void* __restrict__ Cg,
    long sA, long sB, long sC) {
  __shared__ __align__(16) char smem[131072];
  const int NT = 16;  // K=1024 / 64

  int bi, bj, b;
  if (MODE == 0) {
    bi = blockIdx.x; bj = blockIdx.y; b = 0;
  } else {
    int t = blockIdx.x % 136;
    b = blockIdx.x / 136;
    int r = (int)((sqrtf(8.0f * t + 1.0f) - 1.0f) * 0.5f);
    while ((r + 1) * (r + 2) / 2 <= t) r++;
    while (r * (r + 1) / 2 > t) r--;
    bi = r; bj = t - r * (r + 1) / 2;
  }

  const unsigned short* A = Ag + (long)b * sA;
  const unsigned short* Bm = Bg + (long)b * sB;

  const int tid = threadIdx.x;
  const int l = tid & 63, w = tid >> 6;
  const int wr = w >> 2, wc = w & 3;
  const int lr = l & 15, g16 = (l >> 4) * 16;
  const int rowA0 = bi * 256, rowB0 = bj * 256;
  const int laneswz = lr * 64 + (g16 ^ (((lr >> 1) & 3) << 4));
  const int baseA = wr * 8192 + laneswz;
  const int baseB = wc * 4096 + laneswz;

  char* A0 = smem;
  char* B0 = smem + 32768;
  char* A1 = smem + 65536;
  char* B1 = smem + 98304;

  float4v acc[8][4];
#pragma unroll
  for (int i = 0; i < 8; i++)
#pragma unroll
    for (int j = 0; j < 4; j++) acc[i][j] = (float4v){0.f, 0.f, 0.f, 0.f};

  // prologue: tile0 full + tile1's B-k0, A-k0, B-k1 ; certify tile0 ; s1 reads
  stage_half(A, rowA0, 0, 0, A0, tid);
  stage_half(Bm, rowB0, 0, 0, B0, tid);
  stage_half(A, rowA0, 0, 1, A0, tid);
  stage_half(Bm, rowB0, 0, 1, B0, tid);
  stage_half(Bm, rowB0, 1, 0, B1, tid);
  stage_half(A, rowA0, 1, 0, A1, tid);
  stage_half(Bm, rowB0, 1, 1, B1, tid);
  asm volatile("s_waitcnt vmcnt(6)" ::: "memory");
  __builtin_amdgcn_s_barrier();

  short8 A0r, A1r, A2r, A3r, A4r, A5r, A6r, A7r;
  short8 B00, B01, B02, B03, B10, B11, B12, B13;
  LDB(B00, B0, 0, 0); LDB(B01, B0, 0, 1); LDB(B02, B0, 0, 2); LDB(B03, B0, 0, 3);
  LDA(A0r, A0, 0, 0); LDA(A1r, A0, 0, 1); LDA(A2r, A0, 0, 2); LDA(A3r, A0, 0, 3);

#pragma unroll 1
  for (int t = 0; t < NT; t += 2) {
    KTILE_RA(A0, B0, A1, B1, t);
    KTILE_RA(A1, B1, A0, B0, t + 1);
  }

  if (MODE == 0) {
    const int sec = bj >> 2;
    const float* bias = sec == 0 ? b0v : (sec == 1 ? b1v : b2v);
    const float scale = sec == 0 ? 0.03125f : 1.0f;
    unsigned short* C = (unsigned short*)Cg + (long)sec * 16777216L;
    const int colbase = (bj & 3) * 256 + wc * 64;
#pragma unroll
    for (int mi = 0; mi < 8; mi++) {
      int rbase = bi * 256 + wr * 128 + mi * 16 + (l >> 4) * 4;
#pragma unroll
      for (int ni = 0; ni < 4; ni++) {
        int col = colbase + ni * 16 + lr;
        float bb = bias[col];
#pragma unroll
        for (int j = 0; j < 4; j++)
          C[(long)(rbase + j) * 1024 + col] = f2b((acc[mi][ni][j] + bb) * scale);
      }
    }
  } else {
    unsigned short* C = (unsigned short*)Cg + (long)b * sC;
#pragma unroll
    for (int mi = 0; mi < 8; mi++) {
      int rbase = bi * 256 + wr * 128 + mi * 16 + (l >> 4) * 4;
#pragma unroll
      for (int ni = 0; ni < 4; ni++) {
        int col = bj * 256 + wc * 64 + ni * 16 + lr;
#pragma unroll
        for (int j = 0; j < 4; j++)
          C[(long)(rbase + j) * 4096 + col] = f2b(acc[mi][ni][j]);
      }
    }
  }
}

// ================= PV: 256x128, read-ahead, paired bi/15-bi K-stream ==========
__device__ __forceinline__ void pv_src(int tt, int NT1, int bi, int bi2,
                                       int* ar, int* kc) {
  if (tt < NT1) { *ar = bi << 8; *kc = tt << 6; }
  else          { *ar = bi2 << 8; *kc = (tt - NT1) << 6; }
}

__device__ __forceinline__ void pv_stageA(const unsigned short* __restrict__ g,
                                          int ar, int kc, int kk, char* tb, int tid) {
#pragma unroll
  for (int j = 0; j < 2; j++) {
    int c = j * 512 + tid;
    int lc = c ^ ((c >> 3) & 3);
    gload_lds16(g + (long)(ar + (lc >> 2)) * 4096 + kc + kk * 32 + (lc & 3) * 8,
                (unsigned short*)(tb + kk * 16384 + (j * 512 + (tid & 448)) * 16));
  }
}

__device__ __forceinline__ void pv_stageB(const unsigned short* __restrict__ g,
                                          int br, int kc, char* tb, int tid) {
#pragma unroll
  for (int kk = 0; kk < 2; kk++) {
    int lc = tid ^ ((tid >> 3) & 3);
    gload_lds16(g + (long)(br + (lc >> 2)) * 4096 + kc + kk * 32 + (lc & 3) * 8,
                (unsigned short*)(tb + kk * 8192 + (tid & 448) * 16));
  }
}

#define LDPA(dst, TB, kk, mi) dst = *(const short8*)((TB) + basePA + (kk) * 16384 + (mi) * 1024)
#define LDPB(dst, TB, kk, ni) dst = *(const short8*)((TB) + basePB + (kk) * 8192 + (ni) * 1024)

#define PMMX(x0, x1, x2, x3, y0, y1, y2, y3) \
  acc[0][0] = MF(x0, y0, acc[0][0]); acc[0][1] = MF(x0, y1, acc[0][1]); \
  acc[0][2] = MF(x0, y2, acc[0][2]); acc[0][3] = MF(x0, y3, acc[0][3]); \
  acc[1][0] = MF(x1, y0, acc[1][0]); acc[1][1] = MF(x1, y1, acc[1][1]); \
  acc[1][2] = MF(x1, y2, acc[1][2]); acc[1][3] = MF(x1, y3, acc[1][3]); \
  acc[2][0] = MF(x2, y0, acc[2][0]); acc[2][1] = MF(x2, y1, acc[2][1]); \
  acc[2][2] = MF(x2, y2, acc[2][2]); acc[2][3] = MF(x2, y3, acc[2][3]); \
  acc[3][0] = MF(x3, y0, acc[3][0]); acc[3][1] = MF(x3, y1, acc[3][1]); \
  acc[3][2] = MF(x3, y2, acc[3][2]); acc[3][3] = MF(x3, y3, acc[3][3]);

// Read-ahead PV tile: all 16 ds_reads up front (counted lgkmcnt lets s2 reads
// retire under MFMA-1); 2 barriers per tile; vmcnt(2) mid-stream.
#define PVTILE_RA(CA, CB, OA, OB, t) do { \
  LDPB(PB00, CB, 0, 0); LDPB(PB01, CB, 0, 1); LDPB(PB02, CB, 0, 2); LDPB(PB03, CB, 0, 3); \
  LDPA(PA00, CA, 0, 0); LDPA(PA01, CA, 0, 1); LDPA(PA02, CA, 0, 2); LDPA(PA03, CA, 0, 3); \
  LDPB(PB10, CB, 1, 0); LDPB(PB11, CB, 1, 1); LDPB(PB12, CB, 1, 2); LDPB(PB13, CB, 1, 3); \
  LDPA(PA10, CA, 1, 0); LDPA(PA11, CA, 1, 1); LDPA(PA12, CA, 1, 2); LDPA(PA13, CA, 1, 3); \
  if ((t) + 1 < 68) { \
    int ar_, kc_; pv_src((t) + 1, NT1, bi, bi2, &ar_, &kc_); \
    pv_stageA(Sb, ar_, kc_, 1, OA, tid); \
    pv_stageB(vTb, brow0, kc_, OB, tid); \
  } \
  __builtin_amdgcn_s_setprio(1); PMMX(PA00, PA01, PA02, PA03, PB00, PB01, PB02, PB03); __builtin_amdgcn_s_setprio(0); \
  __builtin_amdgcn_s_barrier(); \
  if ((t) + 2 < 68) { \
    int ar_, kc_; pv_src((t) + 2, NT1, bi, bi2, &ar_, &kc_); \
    pv_stageA(Sb, ar_, kc_, 0, CA, tid); \
  } \
  __builtin_amdgcn_s_setprio(1); PMMX(PA10, PA11, PA12, PA13, PB10, PB11, PB12, PB13); __builtin_amdgcn_s_setprio(0); \
  if ((t) + 2 < 68) { asm volatile("s_waitcnt vmcnt(2)" ::: "memory"); } \
  else              { asm volatile("s_waitcnt vmcnt(0)" ::: "memory"); } \
  __builtin_amdgcn_s_barrier(); \
} while (0)

#define PV_STORE(row0) do { \
  float* C = Cg + (long)b * 4194304L; \
  _Pragma("unroll") for (int mi = 0; mi < 4; mi++) { \
    int rbase = (row0) + wr * 64 + mi * 16 + (l >> 4) * 4; \
    _Pragma("unroll") for (int ni = 0; ni < 4; ni++) { \
      int col = brow0 + wc * 64 + ni * 16 + lr; \
      _Pragma("unroll") for (int j = 0; j < 4; j++) \
        C[(long)(rbase + j) * 1024 + col] = acc[mi][ni][j]; \
    } \
  } \
} while (0)

__global__ __launch_bounds__(512, 2) void pv8p(const unsigned short* __restrict__ Sg,
                                               const unsigned short* __restrict__ vTg,
                                               float* __restrict__ Cg) {
  __shared__ __align__(16) char smem[98304];
  const int bi = blockIdx.x;        // 0..7 (pairs with 15-bi)
  const int bj = blockIdx.y;        // 0..7 (128 d-cols each)
  const int b = blockIdx.z;
  const int bi2 = 15 - bi;
  const int NT1 = 4 * (bi + 1);     // even; NT1+NT2 = 68

  const unsigned short* Sb = Sg + (long)b * 16777216L;
  const unsigned short* vTb = vTg + (long)b * 4194304L;
  const int brow0 = bj * 128;

  const int tid = threadIdx.x;
  const int l = tid & 63, w = tid >> 6;
  const int wr = w >> 1, wc = w & 1;
  const int lr = l & 15, g16 = (l >> 4) * 16;
  const int laneswz = lr * 64 + (g16 ^ (((lr >> 1) & 3) << 4));
  const int basePA = wr * 4096 + laneswz;
  const int basePB = wc * 4096 + laneswz;

  char* XA = smem;                  // 32KB
  char* YA = smem + 32768;          // 32KB
  char* XB = smem + 65536;          // 16KB
  char* YB = smem + 81920;          // 16KB

  float4v acc[4][4];
#pragma unroll
  for (int i = 0; i < 4; i++)
#pragma unroll
    for (int j = 0; j < 4; j++) acc[i][j] = (float4v){0.f, 0.f, 0.f, 0.f};

  // prologue: tile0 full -> X (6 issues), tile1 A-K0 -> Y (2 issues)
  {
    int ar_, kc_;
    pv_src(0, NT1, bi, bi2, &ar_, &kc_);
    pv_stageA(Sb, ar_, kc_, 0, XA, tid);
    pv_stageA(Sb, ar_, kc_, 1, XA, tid);
    pv_stageB(vTb, brow0, kc_, XB, tid);
    pv_src(1, NT1, bi, bi2, &ar_, &kc_);
    pv_stageA(Sb, ar_, kc_, 0, YA, tid);
  }
  asm volatile("s_waitcnt vmcnt(2)" ::: "memory");
  __builtin_amdgcn_s_barrier();

  short8 PA00, PA01, PA02, PA03, PA10, PA11, PA12, PA13;
  short8 PB00, PB01, PB02, PB03, PB10, PB11, PB12, PB13;

#pragma unroll 1
  for (int t = 0; t < 68; t += 2) {
    if (t == NT1) {   // part-1 done (NT1 even): store + reset, stream continues
      PV_STORE(bi * 256);
#pragma unroll
      for (int i = 0; i < 4; i++)
#pragma unroll
        for (int j = 0; j < 4; j++) acc[i][j] = (float4v){0.f, 0.f, 0.f, 0.f};
    }
    PVTILE_RA(XA, XB, YA, YB, t);
    PVTILE_RA(YA, YB, XA, XB, t + 1);
  }
  PV_STORE(bi2 * 256);
}

// ---------------- causal softmax, in place on bf16 S (pad to 256-boundary) ---
__global__ __launch_bounds__(256) void softmax_causal(unsigned short* __restrict__ S) {
  const int bid = blockIdx.x;
  const int b = bid >> 12, i = bid & 4095;
  unsigned short* row = S + ((long)b * 4096 + i) * 4096;
  const int len = i + 1;
  const int padTo = ((i >> 8) + 1) << 8;  // 256-boundary for 256-row PV tiles
  const int nch = padTo >> 3;
  const int tid = threadIdx.x;
  const int w = tid >> 6;

  float v[2][8];
  int nc[2];
  float m = -3e38f;
#pragma unroll
  for (int s = 0; s < 2; s++) {
    int c = tid + s * 256;
    nc[s] = -1;
    if (c < nch) {
      nc[s] = c;
      short8 x = *(const short8*)&row[c * 8];
#pragma unroll
      for (int j = 0; j < 8; j++) {
        int idx = c * 8 + j;
        float f = (idx < len) ? b2f((unsigned short)x[j]) : -3e38f;
        v[s][j] = f;
        m = fmaxf(m, f);
      }
    }
  }

  __shared__ float red[4];
#pragma unroll
  for (int off = 32; off; off >>= 1) m = fmaxf(m, __shfl_xor(m, off));
  if ((tid & 63) == 0) red[w] = m;
  __syncthreads();
  m = fmaxf(fmaxf(red[0], red[1]), fmaxf(red[2], red[3]));

  float sum = 0.f;
#pragma unroll
  for (int s = 0; s < 2; s++) {
    if (nc[s] >= 0) {
#pragma unroll
      for (int j = 0; j < 8; j++) {
        float e = __expf(v[s][j] - m);
        v[s][j] = e;
        sum += e;
      }
    }
  }
  __syncthreads();
#pragma unroll
  for (int off = 32; off; off >>= 1) sum += __shfl_xor(sum, off);
  if ((tid & 63) == 0) red[w] = sum;
  __syncthreads();
  sum = red[0] + red[1] + red[2] + red[3];
  const float inv = 1.0f / sum;

#pragma unroll
  for (int s = 0; s < 2; s++) {
    if (nc[s] >= 0) {
      int c = nc[s];
      short8 o;
#pragma unroll
      for (int j = 0; j < 8; j++) o[j] = (short)f2b(v[s][j] * inv);
      *(short8*)&row[c * 8] = o;
    }
  }
}

// ---------------- v transpose: [4][4096][1024] -> [4][1024][4096] ------------
__global__ __launch_bounds__(256) void transpose_v(const unsigned short* __restrict__ V,
                                                   unsigned short* __restrict__ VT) {
  __shared__ unsigned short t[64][65];
  const int b = blockIdx.z;
  const int n0 = blockIdx.x * 64;
  const int d0 = blockIdx.y * 64;
  const unsigned short* Vb = V + (long)b * 4096 * 1024;
  unsigned short* VTb = VT + (long)b * 1024 * 4096;
  const int tid = threadIdx.x;
#pragma unroll
  for (int s = 0; s < 2; s++) {
    int c = s * 256 + tid;
    int r = c >> 3, c8 = (c & 7) * 8;
    short8 x = *(const short8*)&Vb[(long)(n0 + r) * 1024 + d0 + c8];
#pragma unroll
    for (int j = 0; j < 8; j++) t[r][c8 + j] = (unsigned short)x[j];
  }
  __syncthreads();
#pragma unroll
  for (int s = 0; s < 2; s++) {
    int c = s * 256 + tid;
    int dr = c >> 3, n8 = (c & 7) * 8;
    short8 o;
#pragma unroll
    for (int j = 0; j < 8; j++) o[j] = (short)t[n8 + j][dr];
    *(short8*)&VTb[(long)(d0 + dr) * 4096 + n0 + n8] = o;
  }
}

extern "C" void kernel_launch(void* const* d_in, const int* in_sizes, int n_in,
                              void* d_out, int out_size, void* d_ws, size_t ws_size,
                              hipStream_t stream) {
  const float* x  = (const float*)d_in[0];
  const float* Wq = (const float*)d_in[1];
  const float* bq = (const float*)d_in[2];
  const float* Wk = (const float*)d_in[3];
  const float* bk = (const float*)d_in[4];
  const float* Wv = (const float*)d_in[5];
  const float* bv = (const float*)d_in[6];
  float* out = (float*)d_out;

  const long NTOK = 16384L;
  const long D = 1024L;
  const long NB = 4096L;

  unsigned short* ws = (unsigned short*)d_ws;
  unsigned short* qb = ws;                    // q|k|v contiguous 3x[16384,1024]
  unsigned short* kb = qb + NTOK * D;
  unsigned short* vb = kb + NTOK * D;
  unsigned short* vT = vb + NTOK * D;         // [4][1024][4096]
  unsigned short* S  = vT + NTOK * D;         // [4][4096][4096] bf16
  unsigned short* xb  = S;                    // overlaps S (consumed first)
  unsigned short* Wb  = S + NTOK * D;         // concat Wq|Wk|Wv [3072,1024]

  cvt_all<<<2048 + 3 * 256, 256, 0, stream>>>(x, Wq, Wk, Wv, xb, Wb);

  gemm8p<0><<<dim3(64, 12), 512, 0, stream>>>(xb, Wb, bq, bk, bv, qb, 0, 0, 0);

  transpose_v<<<dim3(64, 16, 4), 256, 0, stream>>>(vb, vT);

  gemm8p<1><<<544, 512, 0, stream>>>(qb, kb, nullptr, nullptr, nullptr, S,
      NB * D, NB * D, NB * NB);

  softmax_causal<<<16384, 256, 0, stream>>>(S);

  pv8p<<<dim3(8, 8, 4), 512, 0, stream>>>(S, vT, out);
}

// Round 7
// 433.675 us; speedup vs baseline: 1.5992x; 1.5992x over previous
//
#include <hip/hip_runtime.h>
#include <hip/hip_bf16.h>
#include <stdint.h>

// SelfAttention: B=4, N=4096, D=1024, causal, fp32 in/out.
// R7 = R5 base (R6 read-ahead spilled: 128-arch-VGPR wall) + direct-transposed
// V write in QKV epilogue (drops transpose_v) + bijective XCD swizzle on the
// QKV (bi-major logical) and S grids.

typedef __attribute__((ext_vector_type(8))) short short8;
typedef __attribute__((ext_vector_type(4))) float float4v;

__device__ inline unsigned short f2b(float f) {
  union { float f; unsigned u; } v; v.f = f;
  unsigned r = (v.u + 0x7fffu + ((v.u >> 16) & 1u)) >> 16;
  return (unsigned short)r;
}
__device__ inline float b2f(unsigned short b) {
  union { unsigned u; float f; } v; v.u = ((unsigned)b) << 16;
  return v.f;
}

typedef const __attribute__((address_space(1))) unsigned int* gptr_t;
typedef __attribute__((address_space(3))) unsigned int* lptr_t;

__device__ inline void gload_lds16(const unsigned short* g, unsigned short* l) {
  __builtin_amdgcn_global_load_lds((gptr_t)(const void*)g, (lptr_t)(void*)l, 16, 0, 0);
}

// ---------------- f32 -> bf16 conversion, all 4 tensors in one launch --------
__global__ __launch_bounds__(256) void cvt_all(const float* __restrict__ x,
                                               const float* __restrict__ wq,
                                               const float* __restrict__ wk,
                                               const float* __restrict__ wv,
                                               unsigned short* __restrict__ xb,
                                               unsigned short* __restrict__ wb) {
  const float* src;
  unsigned short* dst;
  long n, i0, stride;
  if (blockIdx.x < 2048) {
    src = x; dst = xb; n = 16384L * 1024;
    i0 = ((long)blockIdx.x * 256 + threadIdx.x) * 4;
    stride = 2048L * 256 * 4;
  } else {
    int wsec = (blockIdx.x - 2048) >> 8;
    int blk = (blockIdx.x - 2048) & 255;
    src = wsec == 0 ? wq : (wsec == 1 ? wk : wv);
    dst = wb + (long)wsec * 1024 * 1024;
    n = 1024L * 1024;
    i0 = ((long)blk * 256 + threadIdx.x) * 4;
    stride = 256L * 256 * 4;
  }
  for (long i = i0; i < n; i += stride) {
    float4 f = *(const float4*)&src[i];
    union { unsigned short u[4]; uint2 v; } o;
    o.u[0] = f2b(f.x); o.u[1] = f2b(f.y); o.u[2] = f2b(f.z); o.u[3] = f2b(f.w);
    *(uint2*)&dst[i] = o.v;
  }
}

// ================= 256x256 / BK=64 / 8-wave 8-phase GEMM (QKV + S) ============
__device__ __forceinline__ void stage_half(const unsigned short* __restrict__ g,
                                           int grow0, int tile, int kk,
                                           char* tb, int tid) {
  const int kc = tile * 64 + kk * 32;
#pragma unroll
  for (int j = 0; j < 2; j++) {
    int c = j * 512 + tid;
    int lc = c ^ ((c >> 3) & 3);  // inverse of read-side swizzle, chunk-granular
    gload_lds16(g + (long)(grow0 + (lc >> 2)) * 1024 + kc + (lc & 3) * 8,
                (unsigned short*)(tb + kk * 16384 + (j * 512 + (tid & 448)) * 16));
  }
}

#define DSA(dst, TB, kk, mi) do { \
  int o = (kk) * 16384 + (wr * 128 + (mi) * 16 + lr) * 64 + g16; \
  o ^= ((o >> 3) & 0x30); dst = *(const short8*)((TB) + o); } while (0)
#define DSB(dst, TB, kk, ni) do { \
  int o = (kk) * 16384 + (wc * 64 + (ni) * 16 + lr) * 64 + g16; \
  o ^= ((o >> 3) & 0x30); dst = *(const short8*)((TB) + o); } while (0)

#define MF(x, y, z) __builtin_amdgcn_mfma_f32_16x16x32_bf16(x, y, z, 0, 0, 0)
#define MMQ(M0) \
  acc[M0 + 0][0] = MF(a0, b0, acc[M0 + 0][0]); \
  acc[M0 + 0][1] = MF(a0, b1, acc[M0 + 0][1]); \
  acc[M0 + 0][2] = MF(a0, b2, acc[M0 + 0][2]); \
  acc[M0 + 0][3] = MF(a0, b3, acc[M0 + 0][3]); \
  acc[M0 + 1][0] = MF(a1, b0, acc[M0 + 1][0]); \
  acc[M0 + 1][1] = MF(a1, b1, acc[M0 + 1][1]); \
  acc[M0 + 1][2] = MF(a1, b2, acc[M0 + 1][2]); \
  acc[M0 + 1][3] = MF(a1, b3, acc[M0 + 1][3]); \
  acc[M0 + 2][0] = MF(a2, b0, acc[M0 + 2][0]); \
  acc[M0 + 2][1] = MF(a2, b1, acc[M0 + 2][1]); \
  acc[M0 + 2][2] = MF(a2, b2, acc[M0 + 2][2]); \
  acc[M0 + 2][3] = MF(a2, b3, acc[M0 + 2][3]); \
  acc[M0 + 3][0] = MF(a3, b0, acc[M0 + 3][0]); \
  acc[M0 + 3][1] = MF(a3, b1, acc[M0 + 3][1]); \
  acc[M0 + 3][2] = MF(a3, b2, acc[M0 + 3][2]); \
  acc[M0 + 3][3] = MF(a3, b3, acc[M0 + 3][3]);

#define KTILE(AT, BT, OA, t) do { \
  short8 a0, a1, a2, a3, b0, b1, b2, b3; \
  DSB(b0, BT, 0, 0); DSB(b1, BT, 0, 1); DSB(b2, BT, 0, 2); DSB(b3, BT, 0, 3); \
  DSA(a0, AT, 0, 0); DSA(a1, AT, 0, 1); DSA(a2, AT, 0, 2); DSA(a3, AT, 0, 3); \
  if ((t) + 1 < NT) stage_half(A, rowA0, (t) + 1, 1, OA, tid); \
  __builtin_amdgcn_s_barrier(); \
  __builtin_amdgcn_s_setprio(1); MMQ(0); __builtin_amdgcn_s_setprio(0); \
  __builtin_amdgcn_s_barrier(); \
  DSA(a0, AT, 0, 4); DSA(a1, AT, 0, 5); DSA(a2, AT, 0, 6); DSA(a3, AT, 0, 7); \
  if ((t) + 2 < NT) stage_half(Bm, rowB0, (t) + 2, 0, BT, tid); \
  __builtin_amdgcn_s_barrier(); \
  __builtin_amdgcn_s_setprio(1); MMQ(4); __builtin_amdgcn_s_setprio(0); \
  __builtin_amdgcn_s_barrier(); \
  DSB(b0, BT, 1, 0); DSB(b1, BT, 1, 1); DSB(b2, BT, 1, 2); DSB(b3, BT, 1, 3); \
  DSA(a0, AT, 1, 0); DSA(a1, AT, 1, 1); DSA(a2, AT, 1, 2); DSA(a3, AT, 1, 3); \
  if ((t) + 2 < NT) stage_half(A, rowA0, (t) + 2, 0, AT, tid); \
  __builtin_amdgcn_s_barrier(); \
  __builtin_amdgcn_s_setprio(1); MMQ(0); __builtin_amdgcn_s_setprio(0); \
  __builtin_amdgcn_s_barrier(); \
  DSA(a0, AT, 1, 4); DSA(a1, AT, 1, 5); DSA(a2, AT, 1, 6); DSA(a3, AT, 1, 7); \
  if ((t) + 2 < NT) stage_half(Bm, rowB0, (t) + 2, 1, BT, tid); \
  __builtin_amdgcn_s_barrier(); \
  __builtin_amdgcn_s_setprio(1); MMQ(4); __builtin_amdgcn_s_setprio(0); \
  if ((t) + 2 < NT) { asm volatile("s_waitcnt vmcnt(6)" ::: "memory"); } \
  else               { asm volatile("s_waitcnt vmcnt(0)" ::: "memory"); } \
  __builtin_amdgcn_s_barrier(); \
} while (0)

template <int MODE>
__global__ __launch_bounds__(512, 2) void gemm8p(
    const unsigned short* __restrict__ Ag, const unsigned short* __restrict__ Bg,
    const float* __restrict__ b0v, const float* __restrict__ b1v,
    const float* __restrict__ b2v, void* __restrict__ Cg,
    unsigned short* __restrict__ vTout,
    long sA, long sB, long sC) {
  __shared__ __align__(16) char smem[131072];
  const int NT = 16;  // K=1024 / 64

  int bi, bj, b;
  if (MODE == 0) {
    // 768 blocks; XCD-bijective swizzle (768%8==0); logical order bi-major so
    // each XCD chunk = 8 A-tiles (4MB, L2-resident) x all 12 B-panels.
    int swz = (blockIdx.x & 7) * 96 + (blockIdx.x >> 3);
    bi = swz / 12; bj = swz % 12; b = 0;
  } else {
    // 544 blocks; XCD-bijective swizzle (544%8==0); logical = batch-major
    // tri-packed (same-bi tiles consecutive -> A-panel reuse within XCD).
    int swz = (blockIdx.x & 7) * 68 + (blockIdx.x >> 3);
    b = swz / 136;
    int t = swz % 136;
    int r = (int)((sqrtf(8.0f * t + 1.0f) - 1.0f) * 0.5f);
    while ((r + 1) * (r + 2) / 2 <= t) r++;
    while (r * (r + 1) / 2 > t) r--;
    bi = r; bj = t - r * (r + 1) / 2;
  }

  const unsigned short* A = Ag + (long)b * sA;
  const unsigned short* Bm = Bg + (long)b * sB;

  const int tid = threadIdx.x;
  const int l = tid & 63, w = tid >> 6;
  const int wr = w >> 2, wc = w & 3;
  const int lr = l & 15, g16 = (l >> 4) * 16;
  const int rowA0 = bi * 256, rowB0 = bj * 256;

  char* A0 = smem;
  char* B0 = smem + 32768;
  char* A1 = smem + 65536;
  char* B1 = smem + 98304;

  float4v acc[8][4];
#pragma unroll
  for (int i = 0; i < 8; i++)
#pragma unroll
    for (int j = 0; j < 4; j++) acc[i][j] = (float4v){0.f, 0.f, 0.f, 0.f};

  stage_half(A, rowA0, 0, 0, A0, tid);
  stage_half(Bm, rowB0, 0, 0, B0, tid);
  stage_half(A, rowA0, 0, 1, A0, tid);
  stage_half(Bm, rowB0, 0, 1, B0, tid);
  stage_half(Bm, rowB0, 1, 0, B1, tid);
  stage_half(A, rowA0, 1, 0, A1, tid);
  stage_half(Bm, rowB0, 1, 1, B1, tid);
  asm volatile("s_waitcnt vmcnt(6)" ::: "memory");
  __builtin_amdgcn_s_barrier();

#pragma unroll 1
  for (int t = 0; t < NT; t += 2) {
    KTILE(A0, B0, A1, t);
    KTILE(A1, B1, A0, t + 1);
  }

  if (MODE == 0) {
    const int sec = bj >> 2;
    const float* bias = sec == 0 ? b0v : (sec == 1 ? b1v : b2v);
    const int colbase = (bj & 3) * 256 + wc * 64;
    if (sec < 2) {
      const float scale = sec == 0 ? 0.03125f : 1.0f;
      unsigned short* C = (unsigned short*)Cg + (long)sec * 16777216L;
#pragma unroll
      for (int mi = 0; mi < 8; mi++) {
        int rbase = bi * 256 + wr * 128 + mi * 16 + (l >> 4) * 4;
#pragma unroll
        for (int ni = 0; ni < 4; ni++) {
          int col = colbase + ni * 16 + lr;
          float bb = bias[col];
#pragma unroll
          for (int j = 0; j < 4; j++)
            C[(long)(rbase + j) * 1024 + col] = f2b((acc[mi][ni][j] + bb) * scale);
        }
      }
    } else {
      // v: write directly transposed into vT[4][1024][4096].
      // Lane's 4 j-values = 4 consecutive tokens = contiguous in vT -> 8B store.
#pragma unroll
      for (int mi = 0; mi < 8; mi++) {
        int rbase = bi * 256 + wr * 128 + mi * 16 + (l >> 4) * 4;
        int bb = rbase >> 12;          // 256-row tiles never straddle batches
        int n0 = rbase & 4095;
#pragma unroll
        for (int ni = 0; ni < 4; ni++) {
          int d = colbase + ni * 16 + lr;
          float bv = bias[d];
          union { unsigned short u[4]; uint2 v; } o;
#pragma unroll
          for (int j = 0; j < 4; j++) o.u[j] = f2b(acc[mi][ni][j] + bv);
          *(uint2*)&vTout[(long)bb * 4194304L + (long)d * 4096 + n0] = o.v;
        }
      }
    }
  } else {
    unsigned short* C = (unsigned short*)Cg + (long)b * sC;
#pragma unroll
    for (int mi = 0; mi < 8; mi++) {
      int rbase = bi * 256 + wr * 128 + mi * 16 + (l >> 4) * 4;
#pragma unroll
      for (int ni = 0; ni < 4; ni++) {
        int col = bj * 256 + wc * 64 + ni * 16 + lr;
#pragma unroll
        for (int j = 0; j < 4; j++)
          C[(long)(rbase + j) * 4096 + col] = f2b(acc[mi][ni][j]);
      }
    }
  }
}

// ================= PV: 256x128, 8-phase, paired bi/15-bi K-stream =============
__device__ __forceinline__ void pv_src(int tt, int NT1, int bi, int bi2,
                                       int* ar, int* kc) {
  if (tt < NT1) { *ar = bi << 8; *kc = tt << 6; }
  else          { *ar = bi2 << 8; *kc = (tt - NT1) << 6; }
}

__device__ __forceinline__ void pv_stageA(const unsigned short* __restrict__ g,
                                          int ar, int kc, int kk, char* tb, int tid) {
#pragma unroll
  for (int j = 0; j < 2; j++) {
    int c = j * 512 + tid;
    int lc = c ^ ((c >> 3) & 3);
    gload_lds16(g + (long)(ar + (lc >> 2)) * 4096 + kc + kk * 32 + (lc & 3) * 8,
                (unsigned short*)(tb + kk * 16384 + (j * 512 + (tid & 448)) * 16));
  }
}

__device__ __forceinline__ void pv_stageB(const unsigned short* __restrict__ g,
                                          int br, int kc, char* tb, int tid) {
#pragma unroll
  for (int kk = 0; kk < 2; kk++) {
    int lc = tid ^ ((tid >> 3) & 3);
    gload_lds16(g + (long)(br + (lc >> 2)) * 4096 + kc + kk * 32 + (lc & 3) * 8,
                (unsigned short*)(tb + kk * 8192 + (tid & 448) * 16));
  }
}

#define PDSA(dst, TB, kk, mi) do { \
  int o = (kk) * 16384 + (wr * 64 + (mi) * 16 + lr) * 64 + g16; \
  o ^= ((o >> 3) & 0x30); dst = *(const short8*)((TB) + o); } while (0)
#define PDSB(dst, TB, kk, ni) do { \
  int o = (kk) * 8192 + (wc * 64 + (ni) * 16 + lr) * 64 + g16; \
  o ^= ((o >> 3) & 0x30); dst = *(const short8*)((TB) + o); } while (0)

#define PMM \
  acc[0][0] = MF(a0, b0, acc[0][0]); acc[0][1] = MF(a0, b1, acc[0][1]); \
  acc[0][2] = MF(a0, b2, acc[0][2]); acc[0][3] = MF(a0, b3, acc[0][3]); \
  acc[1][0] = MF(a1, b0, acc[1][0]); acc[1][1] = MF(a1, b1, acc[1][1]); \
  acc[1][2] = MF(a1, b2, acc[1][2]); acc[1][3] = MF(a1, b3, acc[1][3]); \
  acc[2][0] = MF(a2, b0, acc[2][0]); acc[2][1] = MF(a2, b1, acc[2][1]); \
  acc[2][2] = MF(a2, b2, acc[2][2]); acc[2][3] = MF(a2, b3, acc[2][3]); \
  acc[3][0] = MF(a3, b0, acc[3][0]); acc[3][1] = MF(a3, b1, acc[3][1]); \
  acc[3][2] = MF(a3, b2, acc[3][2]); acc[3][3] = MF(a3, b3, acc[3][3]);

#define PVTILE(CA, CB, OA, OB, t) do { \
  short8 a0, a1, a2, a3, b0, b1, b2, b3; \
  PDSB(b0, CB, 0, 0); PDSB(b1, CB, 0, 1); PDSB(b2, CB, 0, 2); PDSB(b3, CB, 0, 3); \
  PDSA(a0, CA, 0, 0); PDSA(a1, CA, 0, 1); PDSA(a2, CA, 0, 2); PDSA(a3, CA, 0, 3); \
  if ((t) + 1 < 68) { \
    int ar_, kc_; pv_src((t) + 1, NT1, bi, bi2, &ar_, &kc_); \
    pv_stageA(Sb, ar_, kc_, 1, OA, tid); \
    pv_stageB(vTb, brow0, kc_, OB, tid); \
  } \
  __builtin_amdgcn_s_barrier(); \
  __builtin_amdgcn_s_setprio(1); PMM; __builtin_amdgcn_s_setprio(0); \
  __builtin_amdgcn_s_barrier(); \
  PDSB(b0, CB, 1, 0); PDSB(b1, CB, 1, 1); PDSB(b2, CB, 1, 2); PDSB(b3, CB, 1, 3); \
  PDSA(a0, CA, 1, 0); PDSA(a1, CA, 1, 1); PDSA(a2, CA, 1, 2); PDSA(a3, CA, 1, 3); \
  if ((t) + 2 < 68) { \
    int ar_, kc_; pv_src((t) + 2, NT1, bi, bi2, &ar_, &kc_); \
    pv_stageA(Sb, ar_, kc_, 0, CA, tid); \
  } \
  __builtin_amdgcn_s_barrier(); \
  __builtin_amdgcn_s_setprio(1); PMM; __builtin_amdgcn_s_setprio(0); \
  if ((t) + 2 < 68) { asm volatile("s_waitcnt vmcnt(2)" ::: "memory"); } \
  else              { asm volatile("s_waitcnt vmcnt(0)" ::: "memory"); } \
  __builtin_amdgcn_s_barrier(); \
} while (0)

#define PV_STORE(row0) do { \
  float* C = Cg + (long)b * 4194304L; \
  _Pragma("unroll") for (int mi = 0; mi < 4; mi++) { \
    int rbase = (row0) + wr * 64 + mi * 16 + (l >> 4) * 4; \
    _Pragma("unroll") for (int ni = 0; ni < 4; ni++) { \
      int col = brow0 + wc * 64 + ni * 16 + lr; \
      _Pragma("unroll") for (int j = 0; j < 4; j++) \
        C[(long)(rbase + j) * 1024 + col] = acc[mi][ni][j]; \
    } \
  } \
} while (0)

__global__ __launch_bounds__(512, 2) void pv8p(const unsigned short* __restrict__ Sg,
                                               const unsigned short* __restrict__ vTg,
                                               float* __restrict__ Cg) {
  __shared__ __align__(16) char smem[98304];
  const int bi = blockIdx.x;        // 0..7 (pairs with 15-bi)
  const int bj = blockIdx.y;        // 0..7 (128 d-cols each)
  const int b = blockIdx.z;
  const int bi2 = 15 - bi;
  const int NT1 = 4 * (bi + 1);     // even; NT1+NT2 = 68

  const unsigned short* Sb = Sg + (long)b * 16777216L;
  const unsigned short* vTb = vTg + (long)b * 4194304L;
  const int brow0 = bj * 128;

  const int tid = threadIdx.x;
  const int l = tid & 63, w = tid >> 6;
  const int wr = w >> 1, wc = w & 1;
  const int lr = l & 15, g16 = (l >> 4) * 16;

  char* XA = smem;                  // 32KB
  char* YA = smem + 32768;          // 32KB
  char* XB = smem + 65536;          // 16KB
  char* YB = smem + 81920;          // 16KB

  float4v acc[4][4];
#pragma unroll
  for (int i = 0; i < 4; i++)
#pragma unroll
    for (int j = 0; j < 4; j++) acc[i][j] = (float4v){0.f, 0.f, 0.f, 0.f};

  {
    int ar_, kc_;
    pv_src(0, NT1, bi, bi2, &ar_, &kc_);
    pv_stageA(Sb, ar_, kc_, 0, XA, tid);
    pv_stageA(Sb, ar_, kc_, 1, XA, tid);
    pv_stageB(vTb, brow0, kc_, XB, tid);
    pv_src(1, NT1, bi, bi2, &ar_, &kc_);
    pv_stageA(Sb, ar_, kc_, 0, YA, tid);
  }
  asm volatile("s_waitcnt vmcnt(2)" ::: "memory");
  __builtin_amdgcn_s_barrier();

#pragma unroll 1
  for (int t = 0; t < 68; t += 2) {
    if (t == NT1) {   // part-1 done (NT1 even): store + reset, stream continues
      PV_STORE(bi * 256);
#pragma unroll
      for (int i = 0; i < 4; i++)
#pragma unroll
        for (int j = 0; j < 4; j++) acc[i][j] = (float4v){0.f, 0.f, 0.f, 0.f};
    }
    PVTILE(XA, XB, YA, YB, t);
    PVTILE(YA, YB, XA, XB, t + 1);
  }
  PV_STORE(bi2 * 256);
}

// ---------------- causal softmax, in place on bf16 S (pad to 256-boundary) ---
__global__ __launch_bounds__(256) void softmax_causal(unsigned short* __restrict__ S) {
  const int bid = blockIdx.x;
  const int b = bid >> 12, i = bid & 4095;
  unsigned short* row = S + ((long)b * 4096 + i) * 4096;
  const int len = i + 1;
  const int padTo = ((i >> 8) + 1) << 8;  // 256-boundary for 256-row PV tiles
  const int nch = padTo >> 3;
  const int tid = threadIdx.x;
  const int w = tid >> 6;

  float v[2][8];
  int nc[2];
  float m = -3e38f;
#pragma unroll
  for (int s = 0; s < 2; s++) {
    int c = tid + s * 256;
    nc[s] = -1;
    if (c < nch) {
      nc[s] = c;
      short8 x = *(const short8*)&row[c * 8];
#pragma unroll
      for (int j = 0; j < 8; j++) {
        int idx = c * 8 + j;
        float f = (idx < len) ? b2f((unsigned short)x[j]) : -3e38f;
        v[s][j] = f;
        m = fmaxf(m, f);
      }
    }
  }

  __shared__ float red[4];
#pragma unroll
  for (int off = 32; off; off >>= 1) m = fmaxf(m, __shfl_xor(m, off));
  if ((tid & 63) == 0) red[w] = m;
  __syncthreads();
  m = fmaxf(fmaxf(red[0], red[1]), fmaxf(red[2], red[3]));

  float sum = 0.f;
#pragma unroll
  for (int s = 0; s < 2; s++) {
    if (nc[s] >= 0) {
#pragma unroll
      for (int j = 0; j < 8; j++) {
        float e = __expf(v[s][j] - m);
        v[s][j] = e;
        sum += e;
      }
    }
  }
  __syncthreads();
#pragma unroll
  for (int off = 32; off; off >>= 1) sum += __shfl_xor(sum, off);
  if ((tid & 63) == 0) red[w] = sum;
  __syncthreads();
  sum = red[0] + red[1] + red[2] + red[3];
  const float inv = 1.0f / sum;

#pragma unroll
  for (int s = 0; s < 2; s++) {
    if (nc[s] >= 0) {
      int c = nc[s];
      short8 o;
#pragma unroll
      for (int j = 0; j < 8; j++) o[j] = (short)f2b(v[s][j] * inv);
      *(short8*)&row[c * 8] = o;
    }
  }
}

extern "C" void kernel_launch(void* const* d_in, const int* in_sizes, int n_in,
                              void* d_out, int out_size, void* d_ws, size_t ws_size,
                              hipStream_t stream) {
  const float* x  = (const float*)d_in[0];
  const float* Wq = (const float*)d_in[1];
  const float* bq = (const float*)d_in[2];
  const float* Wk = (const float*)d_in[3];
  const float* bk = (const float*)d_in[4];
  const float* Wv = (const float*)d_in[5];
  const float* bv = (const float*)d_in[6];
  float* out = (float*)d_out;

  const long NTOK = 16384L;
  const long D = 1024L;
  const long NB = 4096L;

  unsigned short* ws = (unsigned short*)d_ws;
  unsigned short* qb = ws;                    // q|k contiguous (v slot unused)
  unsigned short* kb = qb + NTOK * D;
  unsigned short* vb = kb + NTOK * D;         // unused (v goes straight to vT)
  unsigned short* vT = vb + NTOK * D;         // [4][1024][4096]
  unsigned short* S  = vT + NTOK * D;         // [4][4096][4096] bf16
  unsigned short* xb  = S;                    // overlaps S (consumed first)
  unsigned short* Wb  = S + NTOK * D;         // concat Wq|Wk|Wv [3072,1024]

  cvt_all<<<2048 + 3 * 256, 256, 0, stream>>>(x, Wq, Wk, Wv, xb, Wb);

  // QKV: [16384,1024] x [3072,1024]^T; v written direct-transposed to vT
  gemm8p<0><<<768, 512, 0, stream>>>(xb, Wb, bq, bk, bv, qb, vT, 0, 0, 0);

  // S = q k^T per batch, lower-tri 256^2 tiles (136/batch), XCD-swizzled
  gemm8p<1><<<544, 512, 0, stream>>>(qb, kb, nullptr, nullptr, nullptr, S,
      nullptr, NB * D, NB * D, NB * NB);

  softmax_causal<<<16384, 256, 0, stream>>>(S);

  pv8p<<<dim3(8, 8, 4), 512, 0, stream>>>(S, vT, out);
}